// Round 16
// baseline (486.843 us; speedup 1.0000x reference)
//
#include <hip/hip_runtime.h>

#define E_TOTAL 1000000
#define EMB     128
#define NRBF    16
#define NATOMS  50000
#define APB     40                         // atoms per block (50000 = 40*1250)
#define NBLK    ((NATOMS + 255) / 256)     // scan blocks
#define ECACHE  1536                       // per-block edge cache (mean 800, max ~950)

typedef _Float16 f16x8 __attribute__((ext_vector_type(8)));
typedef _Float16 f16x4 __attribute__((ext_vector_type(4)));
typedef float    f32x4 __attribute__((ext_vector_type(4)));

__device__ __forceinline__ float silu_f(float v) {
    return v * (1.0f / (1.0f + __expf(-v)));
}

// ---------------------------------------------------------------------------
// CSR build: counting sort of edge ids by destination atom.
// ---------------------------------------------------------------------------
__global__ __launch_bounds__(256)
void hist_kernel(const int* __restrict__ idnb, int* __restrict__ counts) {
    const int e = blockIdx.x * 256 + threadIdx.x;
    if (e < E_TOTAL) atomicAdd(&counts[idnb[e]], 1);
}

__global__ __launch_bounds__(256)
void scan1_kernel(const int* __restrict__ counts, int* __restrict__ row_ptr,
                  int* __restrict__ bsums) {
    __shared__ int sd[256];
    const int tid = threadIdx.x;
    const int idx = blockIdx.x * 256 + tid;
    const int v = (idx < NATOMS) ? counts[idx] : 0;
    sd[tid] = v;
    __syncthreads();
#pragma unroll
    for (int off = 1; off < 256; off <<= 1) {
        const int t = (tid >= off) ? sd[tid - off] : 0;
        __syncthreads();
        sd[tid] += t;
        __syncthreads();
    }
    if (idx < NATOMS) row_ptr[idx] = sd[tid] - v;
    if (tid == 255) bsums[blockIdx.x] = sd[255];
}

__global__ __launch_bounds__(256)
void scan2_kernel(int* __restrict__ bsums) {
    __shared__ int sd[256];
    const int tid = threadIdx.x;
    const int v = (tid < NBLK) ? bsums[tid] : 0;
    sd[tid] = v;
    __syncthreads();
#pragma unroll
    for (int off = 1; off < 256; off <<= 1) {
        const int t = (tid >= off) ? sd[tid - off] : 0;
        __syncthreads();
        sd[tid] += t;
        __syncthreads();
    }
    if (tid < NBLK) bsums[tid] = sd[tid] - v;
}

__global__ __launch_bounds__(256)
void scan3_kernel(const int* __restrict__ bsums, int* __restrict__ row_ptr,
                  int* __restrict__ cursor) {
    const int idx = blockIdx.x * 256 + threadIdx.x;
    if (idx < NATOMS) {
        const int r = row_ptr[idx] + bsums[blockIdx.x];
        row_ptr[idx] = r;
        cursor[idx]  = r;
    }
    if (idx == 0) row_ptr[NATOMS] = E_TOTAL;
}

__global__ __launch_bounds__(256)
void scatter_kernel(const int* __restrict__ idnb, int* __restrict__ cursor,
                    int* __restrict__ eidx, int* __restrict__ aidxs) {
    const int e = blockIdx.x * 256 + threadIdx.x;
    if (e < E_TOTAL) {
        const int a = idnb[e];
        const int p = atomicAdd(&cursor[a], 1);
        eidx[p]  = e;
        aidxs[p] = a;
    }
}

// ---------------------------------------------------------------------------
// MFMA edge kernel, BARRIER-FREE main loop. No LDS staging of x/rbf: each
// lane loads its own A-fragment slots straight from global (x[eid][ks*32 +
// lq*8 ..+8]); a block's tile data (32 KB) is L1/L2-hot so the 4x A re-read
// across waves costs ~nothing at HBM. eidx/aidxs block-cached in LDS once
// (single up-front barrier). Waves run fully independently; sAcc LDS-atomics
// are order-free. Lane's sorted position p(mt)=nb+(lm>>2)*16+mt*4+(lm&3)
// reproduces the r10 sigma layout -> carried run-merge epilogue unchanged.
// Numerics identical to r13 (x/rbf single-f16, W split hi/lo, fused gate).
// ---------------------------------------------------------------------------
__global__ __launch_bounds__(256, 2)
void edge_kernel(const float* __restrict__ x,
                 const float* __restrict__ rbf,
                 const int*   __restrict__ eidx,
                 const int*   __restrict__ aidxs,
                 const int*   __restrict__ row_ptr,
                 const float* __restrict__ Wx,
                 const float* __restrict__ bx,
                 const float* __restrict__ Wr,
                 const float* __restrict__ br,
                 const float* __restrict__ c_a,
                 const float* __restrict__ c_b,
                 const float* __restrict__ c_x,
                 float* __restrict__ acc)
{
    __shared__ float sAcc[APB][132];    // 21.1 KB
    __shared__ int   sEid[ECACHE];      // 6 KB  sorted-pos -> edge id
    __shared__ int   sAid[ECACHE];      // 6 KB  sorted-pos -> atom id

    const int tid  = threadIdx.x;
    const int w    = tid >> 6;
    const int lane = tid & 63;
    const int lq   = lane >> 4;
    const int lm   = lane & 15;

    const int aBase = blockIdx.x * APB;
    const int eBeg  = row_ptr[aBase];
    const int eEnd  = row_ptr[aBase + APB];
    const int nEdge = eEnd - eBeg;
    const int ntile = (nEdge + 63) >> 6;

    const float ca = c_a[0];
    const float sc = c_b[0] * c_x[0];
    const int col0 = w * 32 + lm;
    const int col1 = col0 + 16;
    const float bx0 = bx[col0], bx1 = bx[col1];
    const float br0 = br[col0], br1 = br[col1];

    // ---- hoist split-W fragments from global, once per block ----
    f16x8 wxh[4][2], wxl[4][2], wrh[2], wrl[2];
#pragma unroll
    for (int ks = 0; ks < 4; ++ks)
#pragma unroll
        for (int nt = 0; nt < 2; ++nt) {
            const int n = w * 32 + nt * 16 + lm;
            f16x8 h8, l8;
#pragma unroll
            for (int j = 0; j < 8; ++j) {
                const int k = ks * 32 + lq * 8 + j;
                const float v = Wx[k * EMB + n];
                const _Float16 hv = (_Float16)v;
                h8[j] = hv;
                l8[j] = (_Float16)(v - (float)hv);
            }
            wxh[ks][nt] = h8;
            wxl[ks][nt] = l8;
        }
#pragma unroll
    for (int nt = 0; nt < 2; ++nt) {
        const int n = w * 32 + nt * 16 + lm;
        f16x8 h8, l8;
#pragma unroll
        for (int j = 0; j < 8; ++j) {
            const int k = lq * 8 + j;
            const float v = (k < NRBF) ? Wr[k * EMB + n] : 0.f;
            const _Float16 hv = (_Float16)v;
            h8[j] = hv;
            l8[j] = (_Float16)(v - (float)hv);
        }
        wrh[nt] = h8;
        wrl[nt] = l8;
    }

    // init: zero accumulator; fill eidx/aidxs caches (read-only thereafter)
    for (int f = tid; f < APB * 132; f += 256) ((float*)sAcc)[f] = 0.f;
    for (int f = tid; f < ECACHE; f += 256) {
        const bool in = (f < nEdge);
        sEid[f] = in ? eidx[eBeg + f]  : 0;
        sAid[f] = in ? aidxs[eBeg + f] : -1;
    }
    __syncthreads();                    // ONLY barrier before the final store

    // per-lane lookup helpers (clamped; fallback to global beyond cache)
    auto lookup_eid = [&](int p) -> int {
        const int off = p - eBeg;
        return (off < ECACHE) ? sEid[off] : eidx[p];
    };

    // A-fragment slot loads for one mt: 8 float4 of x + 2 float4 of rbf
    auto issue_mt = [&](int nb, int mt, float4 (&px)[8], float4 (&pr)[2],
                        int& relbase_eid) {
        const int pA = min(nb + ((lm >> 2) << 4) + (mt << 2) + (lm & 3), eEnd - 1);
        const int eid = lookup_eid(pA);
        relbase_eid = eid;
        const float* xr = x + (size_t)eid * EMB;
#pragma unroll
        for (int ks = 0; ks < 4; ++ks) {
            px[2 * ks]     = *(const float4*)(xr + ks * 32 + lq * 8);
            px[2 * ks + 1] = *(const float4*)(xr + ks * 32 + lq * 8 + 4);
        }
        if (lq < 2) {
            const float* rr = rbf + (size_t)eid * NRBF + lq * 8;
            pr[0] = *(const float4*)(rr);
            pr[1] = *(const float4*)(rr + 4);
        }
    };

    for (int t = 0; t < ntile; ++t) {
        const int nb = eBeg + t * 64;

        float4 pxE[8], pxO[8];
        float4 prE[2], prO[2];
        int eidE, eidO;

        issue_mt(nb, 0, pxE, prE, eidE);

        // carried run-merge state (lane covers sorted pos lq*16 .. +15)
        int   curA = -2;
        float a0v = 0.f, a1v = 0.f;

#pragma unroll
        for (int mt = 0; mt < 4; ++mt) {
            // issue next mt's loads before consuming current (ILP cover)
            if (mt == 0) issue_mt(nb, 1, pxO, prO, eidO);
            else if (mt == 1) issue_mt(nb, 2, pxE, prE, eidE);
            else if (mt == 2) issue_mt(nb, 3, pxO, prO, eidO);

            const float4 (&px)[8] = (mt & 1) ? pxO : pxE;
            const float4 (&pr)[2] = (mt & 1) ? prO : prE;

            f32x4 hac[2], gac[2];
#pragma unroll
            for (int nt = 0; nt < 2; ++nt) { hac[nt] = 0.f; gac[nt] = 0.f; }

            // g: K=32; lanes lq>=2 supply zero A-fragment (k>=16)
            f16x8 rh;
            if (lq < 2) {
                rh = f16x8{(_Float16)(pr[0].x * ca), (_Float16)(pr[0].y * ca),
                           (_Float16)(pr[0].z * ca), (_Float16)(pr[0].w * ca),
                           (_Float16)(pr[1].x * ca), (_Float16)(pr[1].y * ca),
                           (_Float16)(pr[1].z * ca), (_Float16)(pr[1].w * ca)};
            } else {
                rh = f16x8{(_Float16)0.f, (_Float16)0.f, (_Float16)0.f, (_Float16)0.f,
                           (_Float16)0.f, (_Float16)0.f, (_Float16)0.f, (_Float16)0.f};
            }
#pragma unroll
            for (int nt = 0; nt < 2; ++nt) {
                gac[nt] = __builtin_amdgcn_mfma_f32_16x16x32_f16(rh, wrh[nt], gac[nt], 0, 0, 0);
                gac[nt] = __builtin_amdgcn_mfma_f32_16x16x32_f16(rh, wrl[nt], gac[nt], 0, 0, 0);
            }

            // h: K=128 in 4 ks steps; A-fragment converted in-reg
#pragma unroll
            for (int ks = 0; ks < 4; ++ks) {
                const float4 a = px[2 * ks];
                const float4 b = px[2 * ks + 1];
                const f16x8 xh = {(_Float16)a.x, (_Float16)a.y, (_Float16)a.z, (_Float16)a.w,
                                  (_Float16)b.x, (_Float16)b.y, (_Float16)b.z, (_Float16)b.w};
#pragma unroll
                for (int nt = 0; nt < 2; ++nt) {
                    hac[nt] = __builtin_amdgcn_mfma_f32_16x16x32_f16(xh, wxh[ks][nt], hac[nt], 0, 0, 0);
                    hac[nt] = __builtin_amdgcn_mfma_f32_16x16x32_f16(xh, wxl[ks][nt], hac[nt], 0, 0, 0);
                }
            }

            // ---- epilogue: fused gate, carried run-merge, rare ds_add ----
            float v0[4], v1[4];
#pragma unroll
            for (int r = 0; r < 4; ++r) {
                const float g0 = gac[0][r] + br0, h0 = hac[0][r] + bx0;
                const float g1 = gac[1][r] + br1, h1 = hac[1][r] + bx1;
                const float d0 = (1.f + __expf(-g0)) * (1.f + __expf(-h0));
                const float d1 = (1.f + __expf(-g1)) * (1.f + __expf(-h1));
                v0[r] = sc * g0 * h0 * __builtin_amdgcn_rcpf(d0);
                v1[r] = sc * g1 * h1 * __builtin_amdgcn_rcpf(d1);
            }
#pragma unroll
            for (int r = 0; r < 4; ++r) {
                const int p = nb + (lq << 4) + (mt << 2) + r;  // C row = lq*4+r
                int rel;
                if (p >= eEnd) {
                    rel = -1;
                } else {
                    const int off = p - eBeg;
                    const int a = (off < ECACHE) ? sAid[off] : aidxs[p];
                    rel = a - aBase;
                }
                if (rel != curA) {                  // rarely taken (run ~20)
                    if (curA >= 0) {
                        atomicAdd(&sAcc[curA][col0], a0v);
                        atomicAdd(&sAcc[curA][col1], a1v);
                    }
                    curA = rel; a0v = 0.f; a1v = 0.f;
                }
                a0v += v0[r];
                a1v += v1[r];
            }
        }
        if (curA >= 0) {                            // final flush per tile
            atomicAdd(&sAcc[curA][col0], a0v);
            atomicAdd(&sAcc[curA][col1], a1v);
        }
    }

    __syncthreads();   // all waves' sAcc atomics (or zero-init) visible
#pragma unroll
    for (int it = 0; it < 3; ++it) {
        const int r = (tid >> 4) + it * 16;
        if (r < APB) {
            const int c = (tid & 15) * 8;
            float* dst = acc + (size_t)(aBase + r) * EMB + c;
            *(float4*)(dst)     = *(const float4*)&sAcc[r][c];
            *(float4*)(dst + 4) = *(const float4*)&sAcc[r][c + 4];
        }
    }
}

// ---------------------------------------------------------------------------
// Fused atom MLP: one block owns 128 rows; L1 -> L2 -> L3 -> final dot all
// in-block, intermediates ping-pong between two f16 LDS buffers.
// ---------------------------------------------------------------------------
__global__ __launch_bounds__(256, 2)
void mlp_fused_kernel(const float* __restrict__ X,
                      const float* __restrict__ W1, const float* __restrict__ b1,
                      const float* __restrict__ W2, const float* __restrict__ b2,
                      const float* __restrict__ W3, const float* __restrict__ b3,
                      const float* __restrict__ Wf, const float* __restrict__ cf,
                      float* __restrict__ out, int M)
{
    __shared__ _Float16 sA[128 * 128];  // 32 KB
    __shared__ _Float16 sB[128 * 128];  // 32 KB
    __shared__ float    sOut[128];

    const int tid  = threadIdx.x;
    const int w    = tid >> 6;
    const int lane = tid & 63;
    const int lq   = lane >> 4;
    const int lm   = lane & 15;

    const int base = blockIdx.x * 128;
    const int col0 = w * 32 + lm;
    const int col1 = col0 + 16;
    const float wf0 = Wf[col0], wf1 = Wf[col1];
    const float cfv = cf[0];

    if (tid < 128) sOut[tid] = 0.f;

    // stage X (f32 global) -> sA (f16, XOR-swizzled)
#pragma unroll
    for (int i = 0; i < 16; ++i) {
        const int e = (tid >> 5) + i * 8;            // 0..127
        const int row = min(base + e, M - 1);
        const float4 v = *(const float4*)(X + (size_t)row * EMB + (tid & 31) * 4);
        const int kb = (tid & 31) * 4;
        const int idx = (e * 128 + kb) ^ ((e & 7) << 3);
        f16x4 h4 = {(_Float16)v.x, (_Float16)v.y, (_Float16)v.z, (_Float16)v.w};
        *(f16x4*)&sA[idx] = h4;
    }
    __syncthreads();

    const float* Ws[3] = {W1, W2, W3};
    const float* bs[3] = {b1, b2, b3};

#pragma unroll 1
    for (int L = 0; L < 3; ++L) {
        const _Float16* sIn   = (L & 1) ? sB : sA;
        _Float16*       sDst  = (L & 1) ? sA : sB;
        const float*    W     = Ws[L];
        const float     bb0   = bs[L][col0];
        const float     bb1   = bs[L][col1];

        // hoist split-W fragments for this layer
        f16x8 wh[4][2], wl[4][2];
#pragma unroll
        for (int ks = 0; ks < 4; ++ks)
#pragma unroll
            for (int nt = 0; nt < 2; ++nt) {
                const int n = w * 32 + nt * 16 + lm;
                f16x8 h8, l8;
#pragma unroll
                for (int j = 0; j < 8; ++j) {
                    const int k = ks * 32 + lq * 8 + j;
                    const float v = W[k * EMB + n];
                    const _Float16 hv = (_Float16)v;
                    h8[j] = hv;
                    l8[j] = (_Float16)(v - (float)hv);
                }
                wh[ks][nt] = h8;
                wl[ks][nt] = l8;
            }

#pragma unroll
        for (int sub = 0; sub < 2; ++sub) {
#pragma unroll
            for (int mth = 0; mth < 2; ++mth) {
                f32x4 hac[2][2];
#pragma unroll
                for (int mi = 0; mi < 2; ++mi)
#pragma unroll
                    for (int nt = 0; nt < 2; ++nt) hac[mi][nt] = 0.f;

#pragma unroll
                for (int mi = 0; mi < 2; ++mi) {
                    const int m = sub * 64 + (mth * 2 + mi) * 16 + lm;
#pragma unroll
                    for (int ks = 0; ks < 4; ++ks) {
                        const int xi = (m * 128 + ks * 32 + lq * 8) ^ ((m & 7) << 3);
                        const f16x8 xh = *(const f16x8*)&sIn[xi];
#pragma unroll
                        for (int nt = 0; nt < 2; ++nt) {
                            hac[mi][nt] = __builtin_amdgcn_mfma_f32_16x16x32_f16(xh, wh[ks][nt], hac[mi][nt], 0, 0, 0);
                            hac[mi][nt] = __builtin_amdgcn_mfma_f32_16x16x32_f16(xh, wl[ks][nt], hac[mi][nt], 0, 0, 0);
                        }
                    }
                }

#pragma unroll
                for (int mi = 0; mi < 2; ++mi) {
                    const int rowl = sub * 64 + (mth * 2 + mi) * 16 + lq * 4;
                    if (L < 2) {
#pragma unroll
                        for (int r = 0; r < 4; ++r) {
                            const float o0 = silu_f(hac[mi][0][r] + bb0);
                            const float o1 = silu_f(hac[mi][1][r] + bb1);
                            const int rw = rowl + r;
                            sDst[(rw * 128 + col0) ^ ((rw & 7) << 3)] = (_Float16)o0;
                            sDst[(rw * 128 + col1) ^ ((rw & 7) << 3)] = (_Float16)o1;
                        }
                    } else {
#pragma unroll
                        for (int r = 0; r < 4; ++r) {
                            const float o0 = silu_f(hac[mi][0][r] + bb0);
                            const float o1 = silu_f(hac[mi][1][r] + bb1);
                            float p = o0 * wf0 + o1 * wf1;
#pragma unroll
                            for (int off = 1; off < 16; off <<= 1)
                                p += __shfl_xor(p, off);
                            if (lm == 0 && base + rowl + r < M)
                                atomicAdd(&sOut[rowl + r], p);
                        }
                    }
                }
            }
        }
        __syncthreads();   // layer outputs visible (or sOut atomics done)
    }

    if (tid < 128) {
        const int row = base + tid;
        if (row < M) out[row] = sOut[tid] * cfv;
    }
}

extern "C" void kernel_launch(void* const* d_in, const int* in_sizes, int n_in,
                              void* d_out, int out_size, void* d_ws, size_t ws_size,
                              hipStream_t stream) {
    const float* x    = (const float*)d_in[0];
    const float* rbf  = (const float*)d_in[1];
    const int*   idnb = (const int*)  d_in[2];
    // d_in[3] = n_atoms (fixed 50000)
    const float* Wx   = (const float*)d_in[4];
    const float* bx   = (const float*)d_in[5];
    const float* Wr   = (const float*)d_in[6];
    const float* brf  = (const float*)d_in[7];
    const float* W1   = (const float*)d_in[8];
    const float* b1   = (const float*)d_in[9];
    const float* W2   = (const float*)d_in[10];
    const float* b2   = (const float*)d_in[11];
    const float* W3   = (const float*)d_in[12];
    const float* b3   = (const float*)d_in[13];
    const float* Wf   = (const float*)d_in[14];
    const float* c_a  = (const float*)d_in[15];
    const float* c_b  = (const float*)d_in[16];
    const float* c_x  = (const float*)d_in[17];
    const float* c_f  = (const float*)d_in[18];

    float* out = (float*)d_out;
    float* acc = (float*)d_ws;                        // [NATOMS][128] f32
    float* buf = acc + (size_t)NATOMS * EMB;          // scratch region
    // CSR scratch inside buf (dead once edge_kernel completes)
    int* eidx    = (int*)buf;                         // 1M
    int* aidxs   = eidx + E_TOTAL;                    // 1M
    int* counts  = aidxs + E_TOTAL;                   // NATOMS
    int* row_ptr = counts + NATOMS;                   // NATOMS+1
    int* cursor  = row_ptr + NATOMS + 1;              // NATOMS
    int* bsums   = cursor + NATOMS;                   // NBLK

    hipMemsetAsync(counts, 0, NATOMS * sizeof(int), stream);

    hist_kernel<<<(E_TOTAL + 255) / 256, 256, 0, stream>>>(idnb, counts);
    scan1_kernel<<<NBLK, 256, 0, stream>>>(counts, row_ptr, bsums);
    scan2_kernel<<<1, 256, 0, stream>>>(bsums);
    scan3_kernel<<<NBLK, 256, 0, stream>>>(bsums, row_ptr, cursor);
    scatter_kernel<<<(E_TOTAL + 255) / 256, 256, 0, stream>>>(idnb, cursor, eidx, aidxs);

    edge_kernel<<<NATOMS / APB, 256, 0, stream>>>(x, rbf, eidx, aidxs, row_ptr,
                                                  Wx, bx, Wr, brf,
                                                  c_a, c_b, c_x, acc);

    mlp_fused_kernel<<<(NATOMS + 127) / 128, 256, 0, stream>>>(
        acc, W1, b1, W2, b2, W3, b3, Wf, c_f, out, NATOMS);
}

// Round 17
// 379.144 us; speedup vs baseline: 1.2841x; 1.2841x over previous
//
#include <hip/hip_runtime.h>

#define E_TOTAL 1000000
#define EMB     128
#define NRBF    16
#define NATOMS  50000
#define APB     40                         // atoms per block (50000 = 40*1250)
#define NBLK    ((NATOMS + 255) / 256)     // scan blocks

typedef _Float16 f16x8 __attribute__((ext_vector_type(8)));
typedef _Float16 f16x4 __attribute__((ext_vector_type(4)));
typedef float    f32x4 __attribute__((ext_vector_type(4)));

__device__ __forceinline__ float silu_f(float v) {
    return v * (1.0f / (1.0f + __expf(-v)));
}

// LDS row e holds sorted edge sigma(e): lane-quarter lq's C-rows across the
// 4 mt steps then cover sorted positions lq*16..lq*16+15 consecutively.
__device__ __forceinline__ int sigma64(int e) {
    return (((e & 15) >> 2) << 4) + ((e >> 4) << 2) + (e & 3);
}

// ---------------------------------------------------------------------------
// CSR build: counting sort of edge ids by destination atom.
// ---------------------------------------------------------------------------
__global__ __launch_bounds__(256)
void hist_kernel(const int* __restrict__ idnb, int* __restrict__ counts) {
    const int e = blockIdx.x * 256 + threadIdx.x;
    if (e < E_TOTAL) atomicAdd(&counts[idnb[e]], 1);
}

__global__ __launch_bounds__(256)
void scan1_kernel(const int* __restrict__ counts, int* __restrict__ row_ptr,
                  int* __restrict__ bsums) {
    __shared__ int sd[256];
    const int tid = threadIdx.x;
    const int idx = blockIdx.x * 256 + tid;
    const int v = (idx < NATOMS) ? counts[idx] : 0;
    sd[tid] = v;
    __syncthreads();
#pragma unroll
    for (int off = 1; off < 256; off <<= 1) {
        const int t = (tid >= off) ? sd[tid - off] : 0;
        __syncthreads();
        sd[tid] += t;
        __syncthreads();
    }
    if (idx < NATOMS) row_ptr[idx] = sd[tid] - v;
    if (tid == 255) bsums[blockIdx.x] = sd[255];
}

__global__ __launch_bounds__(256)
void scan2_kernel(int* __restrict__ bsums) {
    __shared__ int sd[256];
    const int tid = threadIdx.x;
    const int v = (tid < NBLK) ? bsums[tid] : 0;
    sd[tid] = v;
    __syncthreads();
#pragma unroll
    for (int off = 1; off < 256; off <<= 1) {
        const int t = (tid >= off) ? sd[tid - off] : 0;
        __syncthreads();
        sd[tid] += t;
        __syncthreads();
    }
    if (tid < NBLK) bsums[tid] = sd[tid] - v;
}

__global__ __launch_bounds__(256)
void scan3_kernel(const int* __restrict__ bsums, int* __restrict__ row_ptr,
                  int* __restrict__ cursor) {
    const int idx = blockIdx.x * 256 + threadIdx.x;
    if (idx < NATOMS) {
        const int r = row_ptr[idx] + bsums[blockIdx.x];
        row_ptr[idx] = r;
        cursor[idx]  = r;
    }
    if (idx == 0) row_ptr[NATOMS] = E_TOTAL;
}

__global__ __launch_bounds__(256)
void scatter_kernel(const int* __restrict__ idnb, int* __restrict__ cursor,
                    int* __restrict__ eidx) {
    const int e = blockIdx.x * 256 + threadIdx.x;
    if (e < E_TOTAL) {
        const int a = idnb[e];
        const int p = atomicAdd(&cursor[a], 1);
        eidx[p] = e;
    }
}

// ---------------------------------------------------------------------------
// MFMA edge kernel (r13-proven structure, locked). Single-buffer LDS,
// 2-barrier tile loop, sigma-permuted C-rows + carried run-merge + fused
// gate. Rel-atom from the block's 40 scalar row_ptr boundaries. Wr single
// f16 (r12-proven numerics: absmax unchanged at 2.44e-4) -> 72 MFMA/tile.
// ---------------------------------------------------------------------------
__global__ __launch_bounds__(256, 2)
void edge_kernel(const float* __restrict__ x,
                 const float* __restrict__ rbf,
                 const int*   __restrict__ eidx,
                 const int*   __restrict__ row_ptr,
                 const float* __restrict__ Wx,
                 const float* __restrict__ bx,
                 const float* __restrict__ Wr,
                 const float* __restrict__ br,
                 const float* __restrict__ c_a,
                 const float* __restrict__ c_b,
                 const float* __restrict__ c_x,
                 float* __restrict__ acc)
{
    __shared__ _Float16 sX[64 * 128];   // 16 KB, XOR-swizzled 8-f16 groups
    __shared__ _Float16 sR[64 * 40];    // 5 KB, stride-40 pad, k>=16 zero
    __shared__ float    sAcc[APB][132]; // 21.1 KB
    __shared__ int      sAid[64];       // rel-atom of sorted pos (tile-local)

    const int tid  = threadIdx.x;
    const int w    = tid >> 6;
    const int lane = tid & 63;
    const int lq   = lane >> 4;
    const int lm   = lane & 15;

    const int aBase = blockIdx.x * APB;

    // scalar row_ptr boundary table (uniform -> SGPRs)
    int rp[APB];
#pragma unroll
    for (int a = 0; a < APB; ++a) rp[a] = row_ptr[aBase + a];
    const int eBeg = rp[0];
    const int eEnd = row_ptr[aBase + APB];
    const int nEdge = eEnd - eBeg;
    const int ntile = (nEdge + 63) >> 6;

    const float ca = c_a[0];
    const float sc = c_b[0] * c_x[0];
    const int col0 = w * 32 + lm;
    const int col1 = col0 + 16;
    const float bx0 = bx[col0], bx1 = bx[col1];
    const float br0 = br[col0], br1 = br[col1];

    // ---- hoist W fragments (Wx split hi/lo; Wr single f16), once/block ----
    f16x8 wxh[4][2], wxl[4][2], wrh[2];
#pragma unroll
    for (int ks = 0; ks < 4; ++ks)
#pragma unroll
        for (int nt = 0; nt < 2; ++nt) {
            const int n = w * 32 + nt * 16 + lm;
            f16x8 h8, l8;
#pragma unroll
            for (int j = 0; j < 8; ++j) {
                const int k = ks * 32 + lq * 8 + j;
                const float v = Wx[k * EMB + n];
                const _Float16 hv = (_Float16)v;
                h8[j] = hv;
                l8[j] = (_Float16)(v - (float)hv);
            }
            wxh[ks][nt] = h8;
            wxl[ks][nt] = l8;
        }
#pragma unroll
    for (int nt = 0; nt < 2; ++nt) {
        const int n = w * 32 + nt * 16 + lm;
        f16x8 h8;
#pragma unroll
        for (int j = 0; j < 8; ++j) {
            const int k = lq * 8 + j;
            h8[j] = (_Float16)((k < NRBF) ? Wr[k * EMB + n] : 0.f);
        }
        wrh[nt] = h8;
    }

    // init LDS: zero accumulator; zero sR k in [16,40)
    for (int f = tid; f < APB * 132; f += 256) ((float*)sAcc)[f] = 0.f;
    for (int f = tid; f < 64 * 24; f += 256)
        sR[(f / 24) * 40 + 16 + (f % 24)] = (_Float16)0.f;

    float4 px[8];
    float4 pr;
    int    prel = -1;

    auto prefetch = [&](int t) {
        const int nb = eBeg + t * 64;
#pragma unroll
        for (int i = 0; i < 8; ++i) {
            const int e = (tid >> 5) + i * 8;            // LDS row
            const int eid = eidx[min(nb + sigma64(e), eEnd - 1)];
            px[i] = *(const float4*)(x + (size_t)eid * EMB + (tid & 31) * 4);
        }
        {
            const int er = tid >> 2;                     // LDS row (rbf)
            const int eid = eidx[min(nb + sigma64(er), eEnd - 1)];
            pr = *(const float4*)(rbf + (size_t)eid * NRBF + (tid & 3) * 4);
        }
        // rel-atom of sorted position nb+tid from scalar boundaries
        if (tid < 64) {
            const int pos = nb + tid;
            if (pos >= eEnd) {
                prel = -1;
            } else {
                int rel = 0;
#pragma unroll
                for (int a = 1; a < APB; ++a) rel += (pos >= rp[a]) ? 1 : 0;
                prel = rel;
            }
        }
    };

    auto write_lds = [&]() {
#pragma unroll
        for (int i = 0; i < 8; ++i) {
            const int e = (tid >> 5) + i * 8;
            const int kb = (tid & 31) * 4;
            const int idx = (e * 128 + kb) ^ ((e & 7) << 3);
            f16x4 h4 = {(_Float16)px[i].x, (_Float16)px[i].y,
                        (_Float16)px[i].z, (_Float16)px[i].w};
            *(f16x4*)&sX[idx] = h4;
        }
        {
            const int er = tid >> 2;
            const int kb = (tid & 3) * 4;
            f16x4 r4 = {(_Float16)(pr.x * ca), (_Float16)(pr.y * ca),
                        (_Float16)(pr.z * ca), (_Float16)(pr.w * ca)};
            *(f16x4*)&sR[er * 40 + kb] = r4;
        }
        if (tid < 64) sAid[tid] = prel;
    };

    if (ntile > 0) prefetch(0);

    for (int t = 0; t < ntile; ++t) {
        __syncthreads();                 // prev tile's readers (or init) done
        write_lds();
        __syncthreads();                 // tile t visible
        if (t + 1 < ntile) prefetch(t + 1);   // in flight during compute

        // run-merge state carried across the whole tile (16-edge span/lane)
        int   curA = -2;
        float a0v = 0.f, a1v = 0.f;

        auto epi = [&](const f32x4 hac[2], const f32x4 gac[2], int mt) {
            const int pbase = lq * 16 + mt * 4;
            float v0[4], v1[4];
#pragma unroll
            for (int r = 0; r < 4; ++r) {
                const float g0 = gac[0][r] + br0, h0 = hac[0][r] + bx0;
                const float g1 = gac[1][r] + br1, h1 = hac[1][r] + bx1;
                const float d0 = (1.f + __expf(-g0)) * (1.f + __expf(-h0));
                const float d1 = (1.f + __expf(-g1)) * (1.f + __expf(-h1));
                v0[r] = sc * g0 * h0 * __builtin_amdgcn_rcpf(d0);
                v1[r] = sc * g1 * h1 * __builtin_amdgcn_rcpf(d1);
            }
#pragma unroll
            for (int r = 0; r < 4; ++r) {
                const int rel = sAid[pbase + r];
                if (rel != curA) {                  // rarely taken (run ~20)
                    if (curA >= 0) {
                        atomicAdd(&sAcc[curA][col0], a0v);
                        atomicAdd(&sAcc[curA][col1], a1v);
                    }
                    curA = rel; a0v = 0.f; a1v = 0.f;
                }
                a0v += v0[r];
                a1v += v1[r];
            }
        };

        auto mfma_mt = [&](f32x4 hac[2], f32x4 gac[2], int mt) {
#pragma unroll
            for (int nt = 0; nt < 2; ++nt) { hac[nt] = 0.f; gac[nt] = 0.f; }
            const int m = mt * 16 + lm;
            const f16x8 rh = *(const f16x8*)&sR[m * 40 + lq * 8];
#pragma unroll
            for (int nt = 0; nt < 2; ++nt)
                gac[nt] = __builtin_amdgcn_mfma_f32_16x16x32_f16(rh, wrh[nt], gac[nt], 0, 0, 0);
#pragma unroll
            for (int ks = 0; ks < 4; ++ks) {
                const int xi = (m * 128 + ks * 32 + lq * 8) ^ ((m & 7) << 3);
                const f16x8 xh = *(const f16x8*)&sX[xi];
#pragma unroll
                for (int nt = 0; nt < 2; ++nt) {
                    hac[nt] = __builtin_amdgcn_mfma_f32_16x16x32_f16(xh, wxh[ks][nt], hac[nt], 0, 0, 0);
                    hac[nt] = __builtin_amdgcn_mfma_f32_16x16x32_f16(xh, wxl[ks][nt], hac[nt], 0, 0, 0);
                }
            }
        };

        // 2-mt groups: two independent MFMA chains in flight per epilogue pair
#pragma unroll
        for (int g = 0; g < 2; ++g) {
            f32x4 hacA[2], gacA[2], hacB[2], gacB[2];
            mfma_mt(hacA, gacA, g * 2);
            mfma_mt(hacB, gacB, g * 2 + 1);
            epi(hacA, gacA, g * 2);
            epi(hacB, gacB, g * 2 + 1);
        }

        if (curA >= 0) {                            // final flush per tile
            atomicAdd(&sAcc[curA][col0], a0v);
            atomicAdd(&sAcc[curA][col1], a1v);
        }
    }

    __syncthreads();   // sAcc atomics (or zero-init) visible
#pragma unroll
    for (int it = 0; it < 3; ++it) {
        const int r = (tid >> 4) + it * 16;
        if (r < APB) {
            const int c = (tid & 15) * 8;
            float* dst = acc + (size_t)(aBase + r) * EMB + c;
            *(float4*)(dst)     = *(const float4*)&sAcc[r][c];
            *(float4*)(dst + 4) = *(const float4*)&sAcc[r][c + 4];
        }
    }
}

// ---------------------------------------------------------------------------
// Fused atom MLP: one block owns 128 rows; L1 -> L2 -> L3 -> final dot all
// in-block, intermediates ping-pong between two f16 LDS buffers.
// ---------------------------------------------------------------------------
__global__ __launch_bounds__(256, 2)
void mlp_fused_kernel(const float* __restrict__ X,
                      const float* __restrict__ W1, const float* __restrict__ b1,
                      const float* __restrict__ W2, const float* __restrict__ b2,
                      const float* __restrict__ W3, const float* __restrict__ b3,
                      const float* __restrict__ Wf, const float* __restrict__ cf,
                      float* __restrict__ out, int M)
{
    __shared__ _Float16 sA[128 * 128];  // 32 KB
    __shared__ _Float16 sB[128 * 128];  // 32 KB
    __shared__ float    sOut[128];

    const int tid  = threadIdx.x;
    const int w    = tid >> 6;
    const int lane = tid & 63;
    const int lq   = lane >> 4;
    const int lm   = lane & 15;

    const int base = blockIdx.x * 128;
    const int col0 = w * 32 + lm;
    const int col1 = col0 + 16;
    const float wf0 = Wf[col0], wf1 = Wf[col1];
    const float cfv = cf[0];

    if (tid < 128) sOut[tid] = 0.f;

    // stage X (f32 global) -> sA (f16, XOR-swizzled)
#pragma unroll
    for (int i = 0; i < 16; ++i) {
        const int e = (tid >> 5) + i * 8;            // 0..127
        const int row = min(base + e, M - 1);
        const float4 v = *(const float4*)(X + (size_t)row * EMB + (tid & 31) * 4);
        const int kb = (tid & 31) * 4;
        const int idx = (e * 128 + kb) ^ ((e & 7) << 3);
        f16x4 h4 = {(_Float16)v.x, (_Float16)v.y, (_Float16)v.z, (_Float16)v.w};
        *(f16x4*)&sA[idx] = h4;
    }
    __syncthreads();

    const float* Ws[3] = {W1, W2, W3};
    const float* bs[3] = {b1, b2, b3};

#pragma unroll 1
    for (int L = 0; L < 3; ++L) {
        const _Float16* sIn   = (L & 1) ? sB : sA;
        _Float16*       sDst  = (L & 1) ? sA : sB;
        const float*    W     = Ws[L];
        const float     bb0   = bs[L][col0];
        const float     bb1   = bs[L][col1];

        // hoist split-W fragments for this layer
        f16x8 wh[4][2], wl[4][2];
#pragma unroll
        for (int ks = 0; ks < 4; ++ks)
#pragma unroll
            for (int nt = 0; nt < 2; ++nt) {
                const int n = w * 32 + nt * 16 + lm;
                f16x8 h8, l8;
#pragma unroll
                for (int j = 0; j < 8; ++j) {
                    const int k = ks * 32 + lq * 8 + j;
                    const float v = W[k * EMB + n];
                    const _Float16 hv = (_Float16)v;
                    h8[j] = hv;
                    l8[j] = (_Float16)(v - (float)hv);
                }
                wh[ks][nt] = h8;
                wl[ks][nt] = l8;
            }

#pragma unroll
        for (int sub = 0; sub < 2; ++sub) {
#pragma unroll
            for (int mth = 0; mth < 2; ++mth) {
                f32x4 hac[2][2];
#pragma unroll
                for (int mi = 0; mi < 2; ++mi)
#pragma unroll
                    for (int nt = 0; nt < 2; ++nt) hac[mi][nt] = 0.f;

#pragma unroll
                for (int mi = 0; mi < 2; ++mi) {
                    const int m = sub * 64 + (mth * 2 + mi) * 16 + lm;
#pragma unroll
                    for (int ks = 0; ks < 4; ++ks) {
                        const int xi = (m * 128 + ks * 32 + lq * 8) ^ ((m & 7) << 3);
                        const f16x8 xh = *(const f16x8*)&sIn[xi];
#pragma unroll
                        for (int nt = 0; nt < 2; ++nt) {
                            hac[mi][nt] = __builtin_amdgcn_mfma_f32_16x16x32_f16(xh, wh[ks][nt], hac[mi][nt], 0, 0, 0);
                            hac[mi][nt] = __builtin_amdgcn_mfma_f32_16x16x32_f16(xh, wl[ks][nt], hac[mi][nt], 0, 0, 0);
                        }
                    }
                }

#pragma unroll
                for (int mi = 0; mi < 2; ++mi) {
                    const int rowl = sub * 64 + (mth * 2 + mi) * 16 + lq * 4;
                    if (L < 2) {
#pragma unroll
                        for (int r = 0; r < 4; ++r) {
                            const float o0 = silu_f(hac[mi][0][r] + bb0);
                            const float o1 = silu_f(hac[mi][1][r] + bb1);
                            const int rw = rowl + r;
                            sDst[(rw * 128 + col0) ^ ((rw & 7) << 3)] = (_Float16)o0;
                            sDst[(rw * 128 + col1) ^ ((rw & 7) << 3)] = (_Float16)o1;
                        }
                    } else {
#pragma unroll
                        for (int r = 0; r < 4; ++r) {
                            const float o0 = silu_f(hac[mi][0][r] + bb0);
                            const float o1 = silu_f(hac[mi][1][r] + bb1);
                            float p = o0 * wf0 + o1 * wf1;
#pragma unroll
                            for (int off = 1; off < 16; off <<= 1)
                                p += __shfl_xor(p, off);
                            if (lm == 0 && base + rowl + r < M)
                                atomicAdd(&sOut[rowl + r], p);
                        }
                    }
                }
            }
        }
        __syncthreads();   // layer outputs visible (or sOut atomics done)
    }

    if (tid < 128) {
        const int row = base + tid;
        if (row < M) out[row] = sOut[tid] * cfv;
    }
}

extern "C" void kernel_launch(void* const* d_in, const int* in_sizes, int n_in,
                              void* d_out, int out_size, void* d_ws, size_t ws_size,
                              hipStream_t stream) {
    const float* x    = (const float*)d_in[0];
    const float* rbf  = (const float*)d_in[1];
    const int*   idnb = (const int*)  d_in[2];
    // d_in[3] = n_atoms (fixed 50000)
    const float* Wx   = (const float*)d_in[4];
    const float* bx   = (const float*)d_in[5];
    const float* Wr   = (const float*)d_in[6];
    const float* brf  = (const float*)d_in[7];
    const float* W1   = (const float*)d_in[8];
    const float* b1   = (const float*)d_in[9];
    const float* W2   = (const float*)d_in[10];
    const float* b2   = (const float*)d_in[11];
    const float* W3   = (const float*)d_in[12];
    const float* b3   = (const float*)d_in[13];
    const float* Wf   = (const float*)d_in[14];
    const float* c_a  = (const float*)d_in[15];
    const float* c_b  = (const float*)d_in[16];
    const float* c_x  = (const float*)d_in[17];
    const float* c_f  = (const float*)d_in[18];

    float* out = (float*)d_out;
    float* acc = (float*)d_ws;                        // [NATOMS][128] f32
    float* buf = acc + (size_t)NATOMS * EMB;          // scratch region
    // CSR scratch inside buf (dead once edge_kernel completes)
    int* eidx    = (int*)buf;                         // 1M
    int* counts  = eidx + E_TOTAL;                    // NATOMS
    int* row_ptr = counts + NATOMS;                   // NATOMS+1
    int* cursor  = row_ptr + NATOMS + 1;              // NATOMS
    int* bsums   = cursor + NATOMS;                   // NBLK

    hipMemsetAsync(counts, 0, NATOMS * sizeof(int), stream);

    hist_kernel<<<(E_TOTAL + 255) / 256, 256, 0, stream>>>(idnb, counts);
    scan1_kernel<<<NBLK, 256, 0, stream>>>(counts, row_ptr, bsums);
    scan2_kernel<<<1, 256, 0, stream>>>(bsums);
    scan3_kernel<<<NBLK, 256, 0, stream>>>(bsums, row_ptr, cursor);
    scatter_kernel<<<(E_TOTAL + 255) / 256, 256, 0, stream>>>(idnb, cursor, eidx);

    edge_kernel<<<NATOMS / APB, 256, 0, stream>>>(x, rbf, eidx, row_ptr,
                                                  Wx, bx, Wr, brf,
                                                  c_a, c_b, c_x, acc);

    mlp_fused_kernel<<<(NATOMS + 127) / 128, 256, 0, stream>>>(
        acc, W1, b1, W2, b2, W3, b3, Wf, c_f, out, NATOMS);
}